// Round 1
// baseline (2511.838 us; speedup 1.0000x reference)
//
#include <hip/hip_runtime.h>
#include <hip/hip_bf16.h>

// Problem constants (fixed by setup_inputs)
#define BB   16      // batches after reshape (= N_t)
#define NQ   1560    // q rows per batch (N_h*N_w)
#define CC   1024    // channels
#define HH   16      // heads
#define DD   64      // head dim
#define NA   256     // keys per batch
#define CE   768     // encoder channels
#define MTOT (BB*NQ) // 24960 total q rows

// ---------------------------------------------------------------------------
// Shared 64x64-tile fp32 GEMM core: computes acc[4][4] for out[row0+.. , col0+..]
//   out[m,n] = sum_k X[m,k] * W[n,k]      (X: [M,KD], W: [N,KD], both row-major)
// 256 threads; thread (ty=tid>>4, tx=tid&15) owns rows m0=ty*4.., cols n0=tx*4..
// ---------------------------------------------------------------------------
template <int KD>
__device__ __forceinline__ void gemm64(const float* __restrict__ X,
                                       const float* __restrict__ W,
                                       int row0, int col0, float acc[4][4]) {
  __shared__ __align__(16) float xs[16][68];  // [k][m], padded stride 68
  __shared__ __align__(16) float ws[16][68];  // [k][n]
  const int tid = threadIdx.x;
  const int sm = tid >> 2;          // 0..63 row within tile (staging)
  const int sk = (tid & 3) << 2;    // 0,4,8,12 (staging k start)
  const int m0 = (tid >> 4) << 2;
  const int n0 = (tid & 15) << 2;
  const float* xrow = X + (row0 + sm) * KD + sk;
  const float* wrow = W + (col0 + sm) * KD + sk;

  for (int k0 = 0; k0 < KD; k0 += 16) {
    const float4 xv = *reinterpret_cast<const float4*>(xrow + k0);
    const float4 wv = *reinterpret_cast<const float4*>(wrow + k0);
    __syncthreads();  // previous iteration's reads done
    xs[sk + 0][sm] = xv.x; xs[sk + 1][sm] = xv.y;
    xs[sk + 2][sm] = xv.z; xs[sk + 3][sm] = xv.w;
    ws[sk + 0][sm] = wv.x; ws[sk + 1][sm] = wv.y;
    ws[sk + 2][sm] = wv.z; ws[sk + 3][sm] = wv.w;
    __syncthreads();
#pragma unroll
    for (int k = 0; k < 16; ++k) {
      const float4 a = *reinterpret_cast<const float4*>(&xs[k][m0]);
      const float4 b = *reinterpret_cast<const float4*>(&ws[k][n0]);
      const float av[4] = {a.x, a.y, a.z, a.w};
      const float bv[4] = {b.x, b.y, b.z, b.w};
#pragma unroll
      for (int i = 0; i < 4; ++i)
#pragma unroll
        for (int j = 0; j < 4; ++j) acc[i][j] = fmaf(av[i], bv[j], acc[i][j]);
    }
  }
}

// ---------------------------------------------------------------------------
// K1: Q = LN_perhead(x @ q_w^T + q_b)   grid = (MTOT/64, HH)
// ---------------------------------------------------------------------------
__global__ __launch_bounds__(256) void qproj_ln_kernel(
    const float* __restrict__ x, const float* __restrict__ w,
    const float* __restrict__ bias, const float* __restrict__ lnw,
    const float* __restrict__ lnb, float* __restrict__ out) {
  float acc[4][4] = {};
  const int row0 = blockIdx.x * 64;
  const int col0 = blockIdx.y * 64;  // head * 64
  gemm64<CC>(x, w, row0, col0, acc);
  const int m0 = ((int)threadIdx.x >> 4) << 2;
  const int n0 = ((int)threadIdx.x & 15) << 2;
  float lw[4], lb[4];
#pragma unroll
  for (int j = 0; j < 4; ++j) {
    const float bb = bias[col0 + n0 + j];
    lw[j] = lnw[n0 + j]; lb[j] = lnb[n0 + j];
#pragma unroll
    for (int i = 0; i < 4; ++i) acc[i][j] += bb;
  }
#pragma unroll
  for (int i = 0; i < 4; ++i) {
    float s = 0.f, ss = 0.f;
#pragma unroll
    for (int j = 0; j < 4; ++j) { s += acc[i][j]; ss += acc[i][j] * acc[i][j]; }
#pragma unroll
    for (int off = 1; off < 16; off <<= 1) {
      s  += __shfl_xor(s, off, 16);
      ss += __shfl_xor(ss, off, 16);
    }
    const float mean = s * (1.f / 64.f);
    const float var  = ss * (1.f / 64.f) - mean * mean;
    const float r    = rsqrtf(var + 1e-6f);
    float4 o;
    o.x = (acc[i][0] - mean) * r * lw[0] + lb[0];
    o.y = (acc[i][1] - mean) * r * lw[1] + lb[1];
    o.z = (acc[i][2] - mean) * r * lw[2] + lb[2];
    o.w = (acc[i][3] - mean) * r * lw[3] + lb[3];
    *reinterpret_cast<float4*>(&out[(row0 + m0 + i) * CC + col0 + n0]) = o;
  }
}

// ---------------------------------------------------------------------------
// K2: KV = enc @ kv_w^T + kv_b; K gets per-head LN (eps 1e-5); writes
//     Kb/Vb in [b][h][na][d] layout.   grid = (4096/64, 32)
// ---------------------------------------------------------------------------
__global__ __launch_bounds__(256) void kvproj_kernel(
    const float* __restrict__ enc, const float* __restrict__ w,
    const float* __restrict__ bias, const float* __restrict__ lnw,
    const float* __restrict__ lnb, float* __restrict__ Kb,
    float* __restrict__ Vb) {
  float acc[4][4] = {};
  const int row0 = blockIdx.x * 64;
  const int ct   = blockIdx.y;      // 0..15 => K heads, 16..31 => V heads
  const int col0 = ct * 64;
  gemm64<CE>(enc, w, row0, col0, acc);
  const int m0 = ((int)threadIdx.x >> 4) << 2;
  const int n0 = ((int)threadIdx.x & 15) << 2;
#pragma unroll
  for (int j = 0; j < 4; ++j) {
    const float bb = bias[col0 + n0 + j];
#pragma unroll
    for (int i = 0; i < 4; ++i) acc[i][j] += bb;
  }
  const bool isK = (ct < HH);
  const int head = isK ? ct : (ct - HH);
  if (isK) {
    float lw[4], lb[4];
#pragma unroll
    for (int j = 0; j < 4; ++j) { lw[j] = lnw[n0 + j]; lb[j] = lnb[n0 + j]; }
#pragma unroll
    for (int i = 0; i < 4; ++i) {
      float s = 0.f, ss = 0.f;
#pragma unroll
      for (int j = 0; j < 4; ++j) { s += acc[i][j]; ss += acc[i][j] * acc[i][j]; }
#pragma unroll
      for (int off = 1; off < 16; off <<= 1) {
        s  += __shfl_xor(s, off, 16);
        ss += __shfl_xor(ss, off, 16);
      }
      const float mean = s * (1.f / 64.f);
      const float var  = ss * (1.f / 64.f) - mean * mean;
      const float r    = rsqrtf(var + 1e-5f);
#pragma unroll
      for (int j = 0; j < 4; ++j)
        acc[i][j] = (acc[i][j] - mean) * r * lw[j] + lb[j];
    }
  }
  float* dst = isK ? Kb : Vb;
#pragma unroll
  for (int i = 0; i < 4; ++i) {
    const int r  = row0 + m0 + i;
    const int b  = r >> 8;          // r / 256
    const int na = r & 255;
    const int addr = ((b * HH + head) * NA + na) * DD + n0;
    float4 o; o.x = acc[i][0]; o.y = acc[i][1]; o.z = acc[i][2]; o.w = acc[i][3];
    *reinterpret_cast<float4*>(&dst[addr]) = o;
  }
}

// ---------------------------------------------------------------------------
// K3: attention. One thread per q row; online softmax over 256 keys staged
//     in LDS 64 at a time. Writes O over Q in place.
//     grid = (7, HH, BB), block = 256
// ---------------------------------------------------------------------------
__global__ __launch_bounds__(256) void attn_kernel(
    const float* __restrict__ Kb, const float* __restrict__ Vb,
    float* __restrict__ Q) {
  const int chunk = blockIdx.x, h = blockIdx.y, b = blockIdx.z;
  const int n = chunk * 256 + (int)threadIdx.x;
  const bool valid = (n < NQ);
  const int qbase = (b * NQ + (valid ? n : 0)) * CC + h * DD;

  float4 qv[16], acc[16];
#pragma unroll
  for (int j = 0; j < 16; ++j) acc[j] = make_float4(0.f, 0.f, 0.f, 0.f);
  if (valid) {
#pragma unroll
    for (int j = 0; j < 16; ++j)
      qv[j] = *reinterpret_cast<const float4*>(&Q[qbase + j * 4]);
  } else {
#pragma unroll
    for (int j = 0; j < 16; ++j) qv[j] = make_float4(0.f, 0.f, 0.f, 0.f);
  }
  float mx = -3.0e38f, l = 0.f;

  __shared__ __align__(16) float Ks[64 * 64];
  __shared__ __align__(16) float Vs[64 * 64];
  const int kvbase = (b * HH + h) * (NA * DD);

  for (int kc = 0; kc < 4; ++kc) {
    __syncthreads();
#pragma unroll
    for (int i = 0; i < 4; ++i) {
      const int e = (i * 256 + (int)threadIdx.x) * 4;
      *reinterpret_cast<float4*>(&Ks[e]) =
          *reinterpret_cast<const float4*>(&Kb[kvbase + kc * 4096 + e]);
      *reinterpret_cast<float4*>(&Vs[e]) =
          *reinterpret_cast<const float4*>(&Vb[kvbase + kc * 4096 + e]);
    }
    __syncthreads();
    if (valid) {
      for (int m = 0; m < 64; ++m) {
        const float4* kr = reinterpret_cast<const float4*>(&Ks[m * 64]);
        float s = 0.f;
#pragma unroll
        for (int j = 0; j < 16; ++j) {
          const float4 kk = kr[j];
          s = fmaf(qv[j].x, kk.x, s); s = fmaf(qv[j].y, kk.y, s);
          s = fmaf(qv[j].z, kk.z, s); s = fmaf(qv[j].w, kk.w, s);
        }
        s *= 0.125f;  // D^-0.5
        const float mn    = fmaxf(mx, s);
        const float alpha = __expf(mx - mn);
        const float p     = __expf(s - mn);
        l = l * alpha + p;
        const float4* vr = reinterpret_cast<const float4*>(&Vs[m * 64]);
#pragma unroll
        for (int j = 0; j < 16; ++j) {
          const float4 vv = vr[j];
          acc[j].x = acc[j].x * alpha + p * vv.x;
          acc[j].y = acc[j].y * alpha + p * vv.y;
          acc[j].z = acc[j].z * alpha + p * vv.z;
          acc[j].w = acc[j].w * alpha + p * vv.w;
        }
        mx = mn;
      }
    }
  }
  if (valid) {
    const float inv = 1.f / l;
#pragma unroll
    for (int j = 0; j < 16; ++j) {
      float4 o;
      o.x = acc[j].x * inv; o.y = acc[j].y * inv;
      o.z = acc[j].z * inv; o.w = acc[j].w * inv;
      *reinterpret_cast<float4*>(&Q[qbase + j * 4]) = o;
    }
  }
}

// ---------------------------------------------------------------------------
// K4: out = O @ proj_w^T + proj_b    grid = (MTOT/64, CC/64)
// ---------------------------------------------------------------------------
__global__ __launch_bounds__(256) void proj_kernel(
    const float* __restrict__ O, const float* __restrict__ w,
    const float* __restrict__ bias, float* __restrict__ out) {
  float acc[4][4] = {};
  const int row0 = blockIdx.x * 64;
  const int col0 = blockIdx.y * 64;
  gemm64<CC>(O, w, row0, col0, acc);
  const int m0 = ((int)threadIdx.x >> 4) << 2;
  const int n0 = ((int)threadIdx.x & 15) << 2;
#pragma unroll
  for (int i = 0; i < 4; ++i) {
    float4 o;
    o.x = acc[i][0] + bias[col0 + n0 + 0];
    o.y = acc[i][1] + bias[col0 + n0 + 1];
    o.z = acc[i][2] + bias[col0 + n0 + 2];
    o.w = acc[i][3] + bias[col0 + n0 + 3];
    *reinterpret_cast<float4*>(&out[(row0 + m0 + i) * CC + col0 + n0]) = o;
  }
}

// ---------------------------------------------------------------------------
extern "C" void kernel_launch(void* const* d_in, const int* in_sizes, int n_in,
                              void* d_out, int out_size, void* d_ws,
                              size_t ws_size, hipStream_t stream) {
  const float* x      = (const float*)d_in[0];
  const float* enc    = (const float*)d_in[1];
  const float* q_w    = (const float*)d_in[2];
  const float* q_b    = (const float*)d_in[3];
  const float* kv_w   = (const float*)d_in[4];
  const float* kv_b   = (const float*)d_in[5];
  const float* proj_w = (const float*)d_in[6];
  const float* proj_b = (const float*)d_in[7];
  const float* qn_w   = (const float*)d_in[8];
  const float* qn_b   = (const float*)d_in[9];
  const float* kn_w   = (const float*)d_in[10];
  const float* kn_b   = (const float*)d_in[11];
  float* out = (float*)d_out;

  // workspace layout (floats): Q/O [MTOT*CC] | K [BB*HH*NA*DD] | V [same]
  float* Q  = (float*)d_ws;
  float* Kb = Q + (size_t)MTOT * CC;
  float* Vb = Kb + (size_t)BB * HH * NA * DD;

  qproj_ln_kernel<<<dim3(MTOT / 64, HH), 256, 0, stream>>>(x, q_w, q_b, qn_w,
                                                           qn_b, Q);
  kvproj_kernel<<<dim3((BB * NA) / 64, 2 * HH), 256, 0, stream>>>(
      enc, kv_w, kv_b, kn_w, kn_b, Kb, Vb);
  attn_kernel<<<dim3(7, HH, BB), 256, 0, stream>>>(Kb, Vb, Q);
  proj_kernel<<<dim3(MTOT / 64, CC / 64), 256, 0, stream>>>(Q, proj_w, proj_b,
                                                            out);
}

// Round 2
// 349.944 us; speedup vs baseline: 7.1778x; 7.1778x over previous
//
#include <hip/hip_runtime.h>
#include <hip/hip_bf16.h>

// Problem constants (fixed by setup_inputs)
#define BB   16      // batches (N_t)
#define NQb  1560    // q rows per batch
#define CC   1024    // channels
#define HH   16      // heads
#define DD   64      // head dim
#define NAk  256     // keys per batch
#define CE   768     // encoder channels
#define MTOT (BB*NQb) // 24960

typedef __attribute__((ext_vector_type(8))) short bf16x8;
typedef __attribute__((ext_vector_type(4))) float f32x4;
typedef unsigned short u16;

__device__ __forceinline__ u16 f2bf(float f) {  // RNE fp32->bf16
  unsigned u = __builtin_bit_cast(unsigned, f);
  u += 0x7FFFu + ((u >> 16) & 1u);
  return (u16)(u >> 16);
}

__device__ __forceinline__ void gl2lds16(const void* g, void* l) {
  __builtin_amdgcn_global_load_lds(
      (const __attribute__((address_space(1))) void*)g,
      (__attribute__((address_space(3))) void*)l, 16, 0, 0);
}

__device__ __forceinline__ f32x4 mfma16(bf16x8 a, bf16x8 b, f32x4 c) {
  return __builtin_amdgcn_mfma_f32_16x16x32_bf16(a, b, c, 0, 0, 0);
}

// ---------------------------------------------------------------------------
// fp32 -> bf16 bulk convert (vectorized float4 -> ushort4)
// ---------------------------------------------------------------------------
__global__ __launch_bounds__(256) void conv_f2b(const float* __restrict__ s,
                                                u16* __restrict__ d, int n4) {
  int i = blockIdx.x * 256 + threadIdx.x;
  if (i >= n4) return;
  float4 v = reinterpret_cast<const float4*>(s)[i];
  ushort4 o;
  o.x = f2bf(v.x); o.y = f2bf(v.y); o.z = f2bf(v.z); o.w = f2bf(v.w);
  reinterpret_cast<ushort4*>(d)[i] = o;
}

// ---------------------------------------------------------------------------
// bf16 MFMA GEMM: out = A[M,KD] @ W[N,KD]^T (+bias, + epilogue)
// 128x128 tile, BK=64, 4 waves (2x2), global_load_lds staging with
// XOR-swizzled LDS (pre-swizzled global source; swizzle: byte ^= (row&7)<<4).
// EPI: 0 = per-head LN (eps 1e-6) -> bf16 o_bf [M,CC]
//      1 = KV: cols<CC get LN (eps 1e-5) -> Kbf[b][h][na][d];
//              cols>=CC -> Vt[b][h][d][na]  (both bf16)
//      2 = bias -> fp32 o_f [M,CC]
// ---------------------------------------------------------------------------
template <int KD, int EPI>
__global__ __launch_bounds__(256) void gemm_bf16(
    const u16* __restrict__ A, const u16* __restrict__ W,
    const float* __restrict__ bias, const float* __restrict__ lnw,
    const float* __restrict__ lnb, u16* __restrict__ o_bf,
    u16* __restrict__ o_bf2, float* __restrict__ o_f) {
  __shared__ u16 As[128 * 64];
  __shared__ u16 Bs[128 * 64];
  const int tid = threadIdx.x;
  const int l = tid & 63, wid = tid >> 6;
  const int wr = wid >> 1, wc = wid & 1;
  const int row0 = blockIdx.x * 128, col0 = blockIdx.y * 128;

  // staging: each thread owns 16B; rows of 128B; 4 issues of 32 rows per tile
  const int srow = tid >> 3;  // 0..31 (+32/issue); srow&7 invariant per issue
  const int scb = ((((tid & 7) * 16) ^ ((srow & 7) << 4)) >> 1);  // elems
  const u16* gA = A + (size_t)(row0 + srow) * KD + scb;
  const u16* gB = W + (size_t)(col0 + srow) * KD + scb;
  char* lA = (char*)As + tid * 16;
  char* lB = (char*)Bs + tid * 16;

  // fragment LDS byte offsets (read side of the same swizzle)
  int aoff[4][2], boff[4][2];
#pragma unroll
  for (int m = 0; m < 4; ++m)
#pragma unroll
    for (int kk = 0; kk < 2; ++kk) {
      int ra = wr * 64 + m * 16 + (l & 15);
      int rb = wc * 64 + m * 16 + (l & 15);
      int cb = (l >> 4) * 16 + kk * 64;
      aoff[m][kk] = ra * 128 + (cb ^ ((ra & 7) << 4));
      boff[m][kk] = rb * 128 + (cb ^ ((rb & 7) << 4));
    }

  f32x4 acc[4][4];
#pragma unroll
  for (int m = 0; m < 4; ++m)
#pragma unroll
    for (int n = 0; n < 4; ++n) acc[m][n] = (f32x4){0.f, 0.f, 0.f, 0.f};

  for (int k0 = 0; k0 < KD; k0 += 64) {
    __syncthreads();  // prior iteration's LDS reads complete
#pragma unroll
    for (int i = 0; i < 4; ++i) {
      gl2lds16(gA + (size_t)i * 32 * KD + k0, lA + i * 4096);
      gl2lds16(gB + (size_t)i * 32 * KD + k0, lB + i * 4096);
    }
    __syncthreads();  // drains vmcnt(0) => staged data visible
    bf16x8 af[4][2], bfr[4][2];
#pragma unroll
    for (int m = 0; m < 4; ++m)
#pragma unroll
      for (int kk = 0; kk < 2; ++kk) {
        af[m][kk]  = *(const bf16x8*)((const char*)As + aoff[m][kk]);
        bfr[m][kk] = *(const bf16x8*)((const char*)Bs + boff[m][kk]);
      }
#pragma unroll
    for (int kk = 0; kk < 2; ++kk)
#pragma unroll
      for (int m = 0; m < 4; ++m)
#pragma unroll
        for (int n = 0; n < 4; ++n)
          acc[m][n] = mfma16(af[m][kk], bfr[n][kk], acc[m][n]);
  }

  const int colw = col0 + wc * 64;  // wave's 64-col block (64-aligned => 1 head)
  float bv[4];
#pragma unroll
  for (int n = 0; n < 4; ++n) bv[n] = bias[colw + n * 16 + (l & 15)];

  if constexpr (EPI == 2) {
#pragma unroll
    for (int m = 0; m < 4; ++m)
#pragma unroll
      for (int reg = 0; reg < 4; ++reg) {
        int grow = row0 + wr * 64 + m * 16 + (l >> 4) * 4 + reg;
#pragma unroll
        for (int n = 0; n < 4; ++n)
          o_f[(size_t)grow * CC + colw + n * 16 + (l & 15)] =
              acc[m][n][reg] + bv[n];
      }
    return;
  }

  if constexpr (EPI == 0) {
    float lwv[4], lbv[4];
#pragma unroll
    for (int n = 0; n < 4; ++n) {
      lwv[n] = lnw[n * 16 + (l & 15)];
      lbv[n] = lnb[n * 16 + (l & 15)];
    }
    const int head = colw >> 6;
#pragma unroll
    for (int m = 0; m < 4; ++m)
#pragma unroll
      for (int reg = 0; reg < 4; ++reg) {
        float tv[4], s = 0.f, ss = 0.f;
#pragma unroll
        for (int n = 0; n < 4; ++n) {
          tv[n] = acc[m][n][reg] + bv[n];
          s += tv[n]; ss += tv[n] * tv[n];
        }
#pragma unroll
        for (int off = 1; off < 16; off <<= 1) {
          s  += __shfl_xor(s, off, 16);
          ss += __shfl_xor(ss, off, 16);
        }
        float mean = s * (1.f / 64.f);
        float var  = ss * (1.f / 64.f) - mean * mean;
        float rs   = rsqrtf(var + 1e-6f);
        int grow = row0 + wr * 64 + m * 16 + (l >> 4) * 4 + reg;
        u16* dst = o_bf + (size_t)grow * CC + head * 64;
#pragma unroll
        for (int n = 0; n < 4; ++n)
          dst[n * 16 + (l & 15)] = f2bf((tv[n] - mean) * rs * lwv[n] + lbv[n]);
      }
    return;
  }

  if constexpr (EPI == 1) {
    const bool isK = (colw < CC);
    const int head = (isK ? colw : (colw - CC)) >> 6;
    if (isK) {
      float lwv[4], lbv[4];
#pragma unroll
      for (int n = 0; n < 4; ++n) {
        lwv[n] = lnw[n * 16 + (l & 15)];
        lbv[n] = lnb[n * 16 + (l & 15)];
      }
#pragma unroll
      for (int m = 0; m < 4; ++m)
#pragma unroll
        for (int reg = 0; reg < 4; ++reg) {
          float tv[4], s = 0.f, ss = 0.f;
#pragma unroll
          for (int n = 0; n < 4; ++n) {
            tv[n] = acc[m][n][reg] + bv[n];
            s += tv[n]; ss += tv[n] * tv[n];
          }
#pragma unroll
          for (int off = 1; off < 16; off <<= 1) {
            s  += __shfl_xor(s, off, 16);
            ss += __shfl_xor(ss, off, 16);
          }
          float mean = s * (1.f / 64.f);
          float var  = ss * (1.f / 64.f) - mean * mean;
          float rs   = rsqrtf(var + 1e-5f);
          int grow = row0 + wr * 64 + m * 16 + (l >> 4) * 4 + reg;
          int bb = grow >> 8, na = grow & 255;
          u16* dst = o_bf + (size_t)((bb * HH + head) * NAk + na) * DD;
#pragma unroll
          for (int n = 0; n < 4; ++n)
            dst[n * 16 + (l & 15)] =
                f2bf((tv[n] - mean) * rs * lwv[n] + lbv[n]);
        }
    } else {
      // V: store transposed Vt[b][h][d][na]
#pragma unroll
      for (int m = 0; m < 4; ++m)
#pragma unroll
        for (int reg = 0; reg < 4; ++reg) {
          int grow = row0 + wr * 64 + m * 16 + (l >> 4) * 4 + reg;
          int bb = grow >> 8, na = grow & 255;
          u16* dst = o_bf2 + (size_t)(bb * HH + head) * DD * NAk + na;
#pragma unroll
          for (int n = 0; n < 4; ++n) {
            int d = n * 16 + (l & 15);
            dst[(size_t)d * NAk] = f2bf(acc[m][n][reg] + bv[n]);
          }
        }
    }
    return;
  }
}

// ---------------------------------------------------------------------------
// MFMA attention: block = (128 q-rows, head, batch); 4 waves x 32 q-rows.
// K [256][64] and Vt [64][256] staged in LDS (XOR-swizzled, 64KB total).
// Full 256-key score tile in registers -> softmax via width-16 shuffles ->
// P round-trips through retired K region (per-wave private 8KB, 2 chunks).
// ---------------------------------------------------------------------------
__global__ __launch_bounds__(256) void attn_mfma(
    const u16* __restrict__ Qbf, const u16* __restrict__ Kbf,
    const u16* __restrict__ Vtbf, u16* __restrict__ Obf) {
  __shared__ u16 KP[16384];   // 32KB: K, later P chunks (per-wave 8KB)
  __shared__ u16 Vts[16384];  // 32KB: Vt
  const int tid = threadIdx.x, l = tid & 63, wid = tid >> 6;
  const int qb = blockIdx.x, h = blockIdx.y, b = blockIdx.z;
  const size_t kvbase = (size_t)(b * HH + h) * (NAk * DD);

  {  // stage K (rows=key,128B) and Vt (rows=d,512B), pre-swizzled source
    const int kr = tid >> 3;
    const int kcb = ((((tid & 7) * 16) ^ ((kr & 7) << 4)) >> 1);
    const int vr = tid >> 5;
    const int vcb = ((((tid & 31) * 16) ^ ((vr & 7) << 4)) >> 1);
    const u16* gK = Kbf + kvbase + (size_t)kr * DD + kcb;
    const u16* gV = Vtbf + kvbase + (size_t)vr * NAk + vcb;
    char* lK = (char*)KP + tid * 16;
    char* lV = (char*)Vts + tid * 16;
#pragma unroll
    for (int i = 0; i < 8; ++i) {
      gl2lds16(gK + i * 32 * DD, lK + i * 4096);
      gl2lds16(gV + i * 8 * NAk, lV + i * 4096);
    }
  }

  // Q fragments straight from global
  bf16x8 qf[2][2];
#pragma unroll
  for (int m = 0; m < 2; ++m) {
    int qrow = qb * 128 + wid * 32 + m * 16 + (l & 15);
    int qrc = min(qrow, NQb - 1);
    const u16* p = Qbf + (size_t)(b * NQb + qrc) * CC + h * DD + (l >> 4) * 8;
#pragma unroll
    for (int kk = 0; kk < 2; ++kk) qf[m][kk] = *(const bf16x8*)(p + kk * 32);
  }
  __syncthreads();  // staging complete (vmcnt drained)

  // S = Q K^T  (per wave: 32 q-rows x 256 keys)
  f32x4 sf[2][16];
#pragma unroll
  for (int m = 0; m < 2; ++m)
#pragma unroll
    for (int n = 0; n < 16; ++n) sf[m][n] = (f32x4){0.f, 0.f, 0.f, 0.f};
#pragma unroll
  for (int n = 0; n < 16; ++n) {
    int key = n * 16 + (l & 15);
    int swz = (key & 7) << 4;
#pragma unroll
    for (int kk = 0; kk < 2; ++kk) {
      bf16x8 kb = *(const bf16x8*)((const char*)KP + key * 128 +
                                   (((l >> 4) * 16 + kk * 64) ^ swz));
#pragma unroll
      for (int m = 0; m < 2; ++m) sf[m][n] = mfma16(qf[m][kk], kb, sf[m][n]);
    }
  }

  // softmax (rows live in (m,reg,l>>4); cols = 16 frags x 16 lanes)
  float mx[2][4], li[2][4];
#pragma unroll
  for (int m = 0; m < 2; ++m)
#pragma unroll
    for (int reg = 0; reg < 4; ++reg) {
      float v = sf[m][0][reg];
#pragma unroll
      for (int n = 1; n < 16; ++n) v = fmaxf(v, sf[m][n][reg]);
#pragma unroll
      for (int off = 1; off < 16; off <<= 1) v = fmaxf(v, __shfl_xor(v, off, 16));
      mx[m][reg] = v;
    }
#pragma unroll
  for (int m = 0; m < 2; ++m)
#pragma unroll
    for (int n = 0; n < 16; ++n)
#pragma unroll
      for (int reg = 0; reg < 4; ++reg)
        sf[m][n][reg] = __expf((sf[m][n][reg] - mx[m][reg]) * 0.125f);
#pragma unroll
  for (int m = 0; m < 2; ++m)
#pragma unroll
    for (int reg = 0; reg < 4; ++reg) {
      float s = 0.f;
#pragma unroll
      for (int n = 0; n < 16; ++n) s += sf[m][n][reg];
#pragma unroll
      for (int off = 1; off < 16; off <<= 1) s += __shfl_xor(s, off, 16);
      li[m][reg] = 1.f / s;
    }
  __syncthreads();  // all K reads done before P overwrites KP

  f32x4 oacc[2][4];
#pragma unroll
  for (int m = 0; m < 2; ++m)
#pragma unroll
    for (int n = 0; n < 4; ++n) oacc[m][n] = (f32x4){0.f, 0.f, 0.f, 0.f};
  const int wbase = wid * 8192;  // per-wave private 8KB P region (bytes)

#pragma unroll
  for (int c = 0; c < 2; ++c) {
    // write P chunk (32 q x 128 keys, bf16, swizzled byte ^= (q&7)<<4)
#pragma unroll
    for (int m = 0; m < 2; ++m)
#pragma unroll
      for (int reg = 0; reg < 4; ++reg) {
        int ql = m * 16 + (l >> 4) * 4 + reg;
        int qs = (ql & 7) << 4;
        char* base = (char*)KP + wbase + ql * 256;
#pragma unroll
        for (int nn = 0; nn < 8; ++nn) {
          int kb2 = (nn * 16 + (l & 15)) * 2;
          *(u16*)(base + (kb2 ^ qs)) = f2bf(sf[m][c * 8 + nn][reg]);
        }
      }
    __syncthreads();
    // PV over this chunk's 128 keys (4 MFMA k-steps of 32)
#pragma unroll
    for (int ks = 0; ks < 4; ++ks) {
      bf16x8 pa[2], vb[4];
#pragma unroll
      for (int m = 0; m < 2; ++m) {
        int ql = m * 16 + (l & 15);
        pa[m] = *(const bf16x8*)((const char*)KP + wbase + ql * 256 +
                                 ((ks * 64 + (l >> 4) * 16) ^ ((ql & 7) << 4)));
      }
#pragma unroll
      for (int n = 0; n < 4; ++n) {
        int d = n * 16 + (l & 15);
        vb[n] = *(const bf16x8*)(
            (const char*)Vts + d * 512 +
            ((c * 256 + ks * 64 + (l >> 4) * 16) ^ ((d & 7) << 4)));
      }
#pragma unroll
      for (int m = 0; m < 2; ++m)
#pragma unroll
        for (int n = 0; n < 4; ++n) oacc[m][n] = mfma16(pa[m], vb[n], oacc[m][n]);
    }
    __syncthreads();
  }

  // epilogue: O = acc / l  -> bf16
#pragma unroll
  for (int m = 0; m < 2; ++m)
#pragma unroll
    for (int reg = 0; reg < 4; ++reg) {
      int qrow = qb * 128 + wid * 32 + m * 16 + (l >> 4) * 4 + reg;
      if (qrow < NQb) {
        u16* dst = Obf + (size_t)(b * NQb + qrow) * CC + h * DD;
        float inv = li[m][reg];
#pragma unroll
        for (int n = 0; n < 4; ++n)
          dst[n * 16 + (l & 15)] = f2bf(oacc[m][n][reg] * inv);
      }
    }
}

// ---------------------------------------------------------------------------
extern "C" void kernel_launch(void* const* d_in, const int* in_sizes, int n_in,
                              void* d_out, int out_size, void* d_ws,
                              size_t ws_size, hipStream_t stream) {
  const float* x      = (const float*)d_in[0];
  const float* enc    = (const float*)d_in[1];
  const float* q_w    = (const float*)d_in[2];
  const float* q_b    = (const float*)d_in[3];
  const float* kv_w   = (const float*)d_in[4];
  const float* kv_b   = (const float*)d_in[5];
  const float* proj_w = (const float*)d_in[6];
  const float* proj_b = (const float*)d_in[7];
  const float* qn_w   = (const float*)d_in[8];
  const float* qn_b   = (const float*)d_in[9];
  const float* kn_w   = (const float*)d_in[10];
  const float* kn_b   = (const float*)d_in[11];
  float* out = (float*)d_out;

  // workspace (bf16 elems): Xbf/Obf | Qbf | Ebf | QW | KVW | PW | K | Vt
  u16* ws = (u16*)d_ws;
  size_t off = 0;
  u16* Xbf  = ws + off; off += (size_t)MTOT * CC;       // 25.56M (also Obf)
  u16* Qbf  = ws + off; off += (size_t)MTOT * CC;
  u16* Ebf  = ws + off; off += (size_t)BB * NAk * CE;   // 3.15M
  u16* QWb  = ws + off; off += (size_t)CC * CC;
  u16* KVWb = ws + off; off += (size_t)2 * CC * CE;
  u16* PWb  = ws + off; off += (size_t)CC * CC;
  u16* Kbf  = ws + off; off += (size_t)BB * HH * NAk * DD;
  u16* Vtbf = ws + off; off += (size_t)BB * HH * NAk * DD;

  auto cvt = [&](const float* s, u16* d, size_t n) {
    int n4 = (int)(n / 4);
    conv_f2b<<<(n4 + 255) / 256, 256, 0, stream>>>(s, d, n4);
  };
  cvt(x, Xbf, (size_t)MTOT * CC);
  cvt(enc, Ebf, (size_t)BB * NAk * CE);
  cvt(q_w, QWb, (size_t)CC * CC);
  cvt(kv_w, KVWb, (size_t)2 * CC * CE);
  cvt(proj_w, PWb, (size_t)CC * CC);

  gemm_bf16<CC, 0><<<dim3(MTOT / 128, CC / 128), 256, 0, stream>>>(
      Xbf, QWb, q_b, qn_w, qn_b, Qbf, nullptr, nullptr);
  gemm_bf16<CE, 1><<<dim3((BB * NAk) / 128, (2 * CC) / 128), 256, 0, stream>>>(
      Ebf, KVWb, kv_b, kn_w, kn_b, Kbf, Vtbf, nullptr);
  attn_mfma<<<dim3((NQb + 127) / 128, HH, BB), 256, 0, stream>>>(Qbf, Kbf,
                                                                 Vtbf, Xbf);
  gemm_bf16<CC, 2><<<dim3(MTOT / 128, CC / 128), 256, 0, stream>>>(
      Xbf, PWb, proj_b, nullptr, nullptr, nullptr, nullptr, out);
}